// Round 3
// baseline (182.823 us; speedup 1.0000x reference)
//
#include <hip/hip_runtime.h>
#include <math.h>

#define CDIM 1024
#define TC   3072
#define BATCH 8
#define NIN   2048   // input rows per batch (class token handled separately)
#define NHEAD 4

// workspace float offsets (every slot is written before read; no zero-init needed)
#define OFF_Q0P 0           // 16*1024 q0 i-chunk partials
#define OFF_WS  16384       // 4*1024  [h][c]
#define OFF_PM  20480       // 1024*4  per-block online-softmax max
#define OFF_PS  24576       // 1024*4  per-block exp-sum
#define OFF_PY  28672       // 1024*4*1024 partial weighted x-sums
#define OFF_YB  4222976     // 8*4*1024 attention-averaged rows
#define OFF_OCP 4255744     // 8(q)*8(b)*1024 oc partials

// ---- q0 partials: q0p[ic][j] = sum_{i in chunk ic} t[i] * Wqkv[i, j] ----
__global__ void k_q0(const float* __restrict__ t, const float* __restrict__ W,
                     float* __restrict__ wsb) {
    int ic = blockIdx.x >> 3, jc = blockIdx.x & 7;   // 16 i-chunks x 8 j-chunks
    int j = jc * 128 + threadIdx.x;
    int i0 = ic * 64;
    float acc = 0.f;
    for (int i = 0; i < 64; ++i)
        acc += t[i0 + i] * W[(size_t)(i0 + i) * TC + j];
    wsb[OFF_Q0P + ic * CDIM + j] = acc;
}

// ---- Ws[h][c] = sum_d Wk[c, h*256+d] * (q0[d^] + bq[d^]) ----
__global__ void k_ws(const float* __restrict__ W, const float* __restrict__ bqkv,
                     float* __restrict__ wsb) {
    int wave = threadIdx.x >> 6, lane = threadIdx.x & 63;
    int c = blockIdx.x, h = wave;
    int d0 = h * 256 + lane * 4;
    float4 wv = *(const float4*)&W[(size_t)c * TC + CDIM + d0];
    float4 q = *(const float4*)&bqkv[d0];
#pragma unroll
    for (int ic = 0; ic < 16; ++ic) {
        float4 p = *(const float4*)&wsb[OFF_Q0P + ic * CDIM + d0];
        q.x += p.x; q.y += p.y; q.z += p.z; q.w += p.w;
    }
    float acc = wv.x * q.x + wv.y * q.y + wv.z * q.z + wv.w * q.w;
    for (int off = 32; off > 0; off >>= 1) acc += __shfl_down(acc, off);
    if (lane == 0) wsb[OFF_WS + h * CDIM + c] = acc;
}

// ---- single pass over X: scores + online softmax + weighted row-sum ----
// 1024 blocks x 256 thr; block = (b, 16-row chunk); wave owns 4 consecutive rows.
__global__ __launch_bounds__(256) void k_pass1(const float* __restrict__ x,
                                               float* __restrict__ wsb) {
    int tid = threadIdx.x, lane = tid & 63, wave = tid >> 6;
    int b = blockIdx.x >> 7, blkc = blockIdx.x & 127;

    float4 wsr[4][4];
#pragma unroll
    for (int k = 0; k < 4; ++k)
#pragma unroll
        for (int h = 0; h < 4; ++h)
            wsr[k][h] = *(const float4*)&wsb[OFF_WS + h * CDIM + k * 256 + lane * 4];

    float m[4], s[4];
    float4 y[4][4];
#pragma unroll
    for (int h = 0; h < 4; ++h) {
        m[h] = -1e30f; s[h] = 0.f;
#pragma unroll
        for (int k = 0; k < 4; ++k) y[h][k] = make_float4(0.f, 0.f, 0.f, 0.f);
    }

    const float* base = x + ((size_t)b * NIN + blkc * 16 + wave * 4) * CDIM;
#pragma unroll 2
    for (int i = 0; i < 4; ++i) {
        const float* row = base + (size_t)i * CDIM;
        float4 xv[4];
#pragma unroll
        for (int k = 0; k < 4; ++k) xv[k] = *(const float4*)&row[k * 256 + lane * 4];
        float d[4];
#pragma unroll
        for (int h = 0; h < 4; ++h) {
            float a = 0.f;
#pragma unroll
            for (int k = 0; k < 4; ++k)
                a += xv[k].x * wsr[k][h].x + xv[k].y * wsr[k][h].y +
                     xv[k].z * wsr[k][h].z + xv[k].w * wsr[k][h].w;
            for (int off = 1; off < 64; off <<= 1) a += __shfl_xor(a, off);
            d[h] = a * 0.0625f;   // Dh=256 -> 1/16; per-head +ck cancels in softmax
        }
#pragma unroll
        for (int h = 0; h < 4; ++h) {
            float sc = d[h], f;
            if (sc > m[h]) {              // wave-uniform branch
                float rs = __expf(m[h] - sc);
                s[h] *= rs;
#pragma unroll
                for (int k = 0; k < 4; ++k) {
                    y[h][k].x *= rs; y[h][k].y *= rs; y[h][k].z *= rs; y[h][k].w *= rs;
                }
                m[h] = sc; f = 1.f;
            } else f = __expf(sc - m[h]);
            s[h] += f;
#pragma unroll
            for (int k = 0; k < 4; ++k) {
                y[h][k].x += f * xv[k].x; y[h][k].y += f * xv[k].y;
                y[h][k].z += f * xv[k].z; y[h][k].w += f * xv[k].w;
            }
        }
    }

    // block merge of 4 wave states via LDS
    __shared__ float ms[4][4], ss[4][4];
    __shared__ float ybuf[4][CDIM];
    if (lane == 0)
#pragma unroll
        for (int h = 0; h < 4; ++h) { ms[wave][h] = m[h]; ss[wave][h] = s[h]; }
    for (int idx = tid; idx < 4 * CDIM; idx += 256) ((float*)ybuf)[idx] = 0.f;
    __syncthreads();
    float mb[4], sb[4], fme[4];
#pragma unroll
    for (int h = 0; h < 4; ++h) {
        mb[h] = fmaxf(fmaxf(ms[0][h], ms[1][h]), fmaxf(ms[2][h], ms[3][h]));
        sb[h] = 0.f;
#pragma unroll
        for (int w = 0; w < 4; ++w) sb[h] += __expf(ms[w][h] - mb[h]) * ss[w][h];
        fme[h] = __expf(m[h] - mb[h]);
    }
    for (int w = 0; w < 4; ++w) {
        if (wave == w) {
#pragma unroll
            for (int h = 0; h < 4; ++h)
#pragma unroll
                for (int k = 0; k < 4; ++k) {
                    float4* dst = (float4*)&ybuf[h][k * 256 + lane * 4];
                    float4 v = *dst;
                    v.x += fme[h] * y[h][k].x; v.y += fme[h] * y[h][k].y;
                    v.z += fme[h] * y[h][k].z; v.w += fme[h] * y[h][k].w;
                    *dst = v;
                }
        }
        __syncthreads();
    }
    int p = blockIdx.x;
    if (tid < 4) { wsb[OFF_PM + p * 4 + tid] = mb[tid]; wsb[OFF_PS + p * 4 + tid] = sb[tid]; }
    for (int idx = tid; idx < 4 * CDIM; idx += 256)
        wsb[OFF_PY + (size_t)p * 4096 + idx] = ((float*)ybuf)[idx];
}

// ---- combine 128 chunk-partials per (b,h) + class-token term -> ybar[b][h][c] ----
__global__ void k_comb(const float* __restrict__ t, float* __restrict__ wsb) {
    int tid = threadIdx.x, lane = tid & 63, wv = tid >> 6;
    int blk = blockIdx.x;
    int b = blk >> 4, h = (blk >> 2) & 3, cq = blk & 3;
    __shared__ float red[4], redM[4], redS[4], fbuf[128];

    // sc0 = (t . Ws_h) / 16
    int c0 = tid * 4;
    float4 tv = *(const float4*)&t[c0];
    float4 wsv = *(const float4*)&wsb[OFF_WS + h * CDIM + c0];
    float p = tv.x * wsv.x + tv.y * wsv.y + tv.z * wsv.z + tv.w * wsv.w;
    for (int off = 1; off < 64; off <<= 1) p += __shfl_xor(p, off);
    if (lane == 0) red[wv] = p;
    __syncthreads();
    float sc0 = (red[0] + red[1] + red[2] + red[3]) * 0.0625f;

    float mv = (tid < 128) ? wsb[OFF_PM + (size_t)(b * 128 + tid) * 4 + h] : -1e30f;
    float mr = mv;
    for (int off = 1; off < 64; off <<= 1) mr = fmaxf(mr, __shfl_xor(mr, off));
    if (lane == 0) redM[wv] = mr;
    __syncthreads();
    float M = fmaxf(fmaxf(fmaxf(redM[0], redM[1]), fmaxf(redM[2], redM[3])), sc0);

    float sv = 0.f;
    if (tid < 128) {
        float fj = __expf(mv - M);
        fbuf[tid] = fj;
        sv = fj * wsb[OFF_PS + (size_t)(b * 128 + tid) * 4 + h];
    }
    for (int off = 1; off < 64; off <<= 1) sv += __shfl_xor(sv, off);
    if (lane == 0) redS[wv] = sv;
    __syncthreads();
    float e0 = __expf(sc0 - M);
    float S = redS[0] + redS[1] + redS[2] + redS[3] + e0;

    int c = cq * 256 + tid;
    float acc = e0 * t[c];
#pragma unroll 4
    for (int j = 0; j < 128; ++j)
        acc += fbuf[j] * wsb[OFF_PY + (size_t)(b * 128 + j) * 4096 + h * CDIM + c];
    wsb[OFF_YB + (size_t)(b * 4 + h) * CDIM + c] = acc / S;
}

// ---- ocp[q][b][c'] partials of ybar[b][h(c')] . Wqkv[:, 2C+c'] ; also zero out ----
__global__ void k_ocy(const float* __restrict__ W, const float* __restrict__ bqkv,
                      float* __restrict__ wsb, float* __restrict__ out) {
    // fold d_out zeroing in here (runs before k_out in stream order)
    out[blockIdx.x * 128 + threadIdx.x] = 0.f;

    int p = blockIdx.x >> 3, q = blockIdx.x & 7;
    int h = p >> 1;
    __shared__ float sL[1024];
    for (int bb = 0; bb < 8; ++bb)
        sL[bb * 128 + threadIdx.x] = wsb[OFF_YB + (size_t)(bb * 4 + h) * CDIM + q * 128 + threadIdx.x];
    __syncthreads();
    int cp = p * 128 + threadIdx.x;
    float acc[8] = {0.f, 0.f, 0.f, 0.f, 0.f, 0.f, 0.f, 0.f};
    for (int c = 0; c < 128; ++c) {
        float wv = W[(size_t)(q * 128 + c) * TC + 2 * CDIM + cp];
#pragma unroll
        for (int bb = 0; bb < 8; ++bb) acc[bb] += sL[bb * 128 + c] * wv;
    }
    if (q == 0) {
        float bias = bqkv[2 * CDIM + cp];
#pragma unroll
        for (int bb = 0; bb < 8; ++bb) acc[bb] += bias;
    }
#pragma unroll
    for (int bb = 0; bb < 8; ++bb)
        wsb[OFF_OCP + (size_t)(q * 8 + bb) * CDIM + cp] = acc[bb];
}

// ---- out[b][j] = oc[b] . Wv[:, j] + bv  (sum ocp q-partials at load) ----
__global__ void k_out(const float* __restrict__ Wv, const float* __restrict__ bv,
                      const float* __restrict__ wsb, float* __restrict__ out) {
    int jp = blockIdx.x >> 3, cq = blockIdx.x & 7;
    __shared__ float ocL[1024];
    for (int bb = 0; bb < 8; ++bb) {
        float sum = 0.f;
#pragma unroll
        for (int q = 0; q < 8; ++q)
            sum += wsb[OFF_OCP + (size_t)(q * 8 + bb) * CDIM + cq * 128 + threadIdx.x];
        ocL[bb * 128 + threadIdx.x] = sum;
    }
    __syncthreads();
    int j = jp * 128 + threadIdx.x;
    float acc[8] = {0.f, 0.f, 0.f, 0.f, 0.f, 0.f, 0.f, 0.f};
    for (int c = 0; c < 128; ++c) {
        float wv = Wv[(size_t)(cq * 128 + c) * CDIM + j];
#pragma unroll
        for (int bb = 0; bb < 8; ++bb) acc[bb] += ocL[bb * 128 + c] * wv;
    }
    if (cq == 0) {
        float bias = bv[j];
#pragma unroll
        for (int bb = 0; bb < 8; ++bb) acc[bb] += bias;
    }
#pragma unroll
    for (int bb = 0; bb < 8; ++bb) atomicAdd(&out[bb * CDIM + j], acc[bb]);
}

extern "C" void kernel_launch(void* const* d_in, const int* in_sizes, int n_in,
                              void* d_out, int out_size, void* d_ws, size_t ws_size,
                              hipStream_t stream) {
    const float* x    = (const float*)d_in[0];   // [8,2048,1024]
    const float* t    = (const float*)d_in[1];   // [1,1,1024]
    const float* Wqkv = (const float*)d_in[2];   // [1024,3072]
    const float* bqkv = (const float*)d_in[3];   // [3072]
    const float* Wv   = (const float*)d_in[4];   // [1024,1024]
    const float* bv   = (const float*)d_in[5];   // [1024]
    float* wsb = (float*)d_ws;
    float* out = (float*)d_out;                  // [8,1024] fp32

    k_q0   <<<128,  128, 0, stream>>>(t, Wqkv, wsb);
    k_ws   <<<1024, 256, 0, stream>>>(Wqkv, bqkv, wsb);
    k_pass1<<<1024, 256, 0, stream>>>(x, wsb);
    k_comb <<<128,  256, 0, stream>>>(t, wsb);
    k_ocy  <<<64,   128, 0, stream>>>(Wqkv, bqkv, wsb, out);
    k_out  <<<64,   128, 0, stream>>>(Wv, bv, wsb, out);
}